// Round 9
// baseline (265.010 us; speedup 1.0000x reference)
//
#include <hip/hip_runtime.h>

typedef unsigned short ushort_t;
typedef __bf16 bf16x8 __attribute__((ext_vector_type(8)));
typedef float floatx4 __attribute__((ext_vector_type(4)));

__device__ inline ushort_t f2bf(float f) {
    __bf16 h = (__bf16)f;
    return __builtin_bit_cast(ushort_t, h);
}

__device__ inline void gload16(const void* g, void* l) {
    __builtin_amdgcn_global_load_lds((const __attribute__((address_space(1))) void*)g,
                                     (__attribute__((address_space(3))) void*)l, 16, 0, 0);
}

// ---------------------------------------------------------------- prep: wt transpose (blocks 0..2303) + cast x (blocks 2304..8447)
__global__ __launch_bounds__(256) void prep_kernel(
    const float* __restrict__ x, ushort_t* __restrict__ xbf,
    const float* __restrict__ W0, const float* __restrict__ W1,
    const float* __restrict__ W2, const float* __restrict__ W3,
    ushort_t* __restrict__ T0, ushort_t* __restrict__ T1,
    ushort_t* __restrict__ T2, ushort_t* __restrict__ T3) {
    int bx = blockIdx.x;
    int tid = threadIdx.x;
    if (bx < 2304) {
        __shared__ float t[32][33];
        int w = bx / 576, rem = bx % 576;
        const float* W; ushort_t* T;
        switch (w) {
            case 0: W = W0; T = T0; break;
            case 1: W = W1; T = T1; break;
            case 2: W = W2; T = T2; break;
            default: W = W3; T = T3; break;
        }
        int n0 = (rem / 24) * 32, k0 = (rem % 24) * 32;
        int tx = tid & 31, ty = tid >> 5;   // 32 x 8
        for (int i = 0; i < 4; ++i)
            t[ty + i * 8][tx] = W[(k0 + ty + i * 8) * 768 + n0 + tx];
        __syncthreads();
        for (int i = 0; i < 4; ++i)
            T[(n0 + ty + i * 8) * 768 + k0 + tx] = f2bf(t[tx][ty + i * 8]);
    } else {
        int i = ((bx - 2304) * 256 + tid) * 4;
        float4 v = *(const float4*)(x + i);
        ushort4 u;
        u.x = f2bf(v.x); u.y = f2bf(v.y); u.z = f2bf(v.z); u.w = f2bf(v.w);
        *(ushort4*)(xbf + i) = u;
    }
}

// ---------------------------------------------------------------- fused QKV GEMM (m97-style staging)
// Q pre-scaled by 0.125*log2(e). For V blocks the MFMA operands are SWAPPED so
// the accumulator holds C^T (rows = weight/dd, cols = token) — the V^T global
// write then has lanes along contiguous ss (4 lines/store instead of 16).
__global__ __launch_bounds__(256) void gemm_qkv(
    const ushort_t* __restrict__ A,
    const ushort_t* __restrict__ Tq, const ushort_t* __restrict__ Tk, const ushort_t* __restrict__ Tv,
    const float* __restrict__ bq, const float* __restrict__ bk, const float* __restrict__ bv,
    ushort_t* __restrict__ Qb, ushort_t* __restrict__ Kb, ushort_t* __restrict__ Vtb) {
    __shared__ ushort_t As[128 * 64];
    __shared__ ushort_t Bs[128 * 64];
    int tid = threadIdx.x;
    int m0 = blockIdx.x * 128;
    int nt = blockIdx.y;       // 0..17
    int which = nt / 6;
    int n0 = (nt % 6) * 128;
    const ushort_t* Bt = which == 0 ? Tq : (which == 1 ? Tk : Tv);
    const float* bias = which == 0 ? bq : (which == 1 ? bk : bv);

    int wave = tid >> 6;
    int lane = tid & 63;
    int ln = tid & 15;
    int quad = (tid >> 4) & 3;
    int wm = (wave & 1) * 64;
    int wn = (wave >> 1) * 64;
    int lr = lane >> 3;          // 0..7
    int lc = (lane & 7) * 8;     // element col in 64

    floatx4 acc[4][4];
    floatx4 z = {0.f, 0.f, 0.f, 0.f};
    for (int i = 0; i < 4; ++i)
        for (int j = 0; j < 4; ++j) acc[i][j] = z;

    for (int kt = 0; kt < 12; ++kt) {
        int k0 = kt * 64;
        __syncthreads();
        for (int i = 0; i < 4; ++i) {
            int c = wave * 4 + i;        // chunk 0..15, rows 8c..8c+7
            int row = c * 8 + lr;
            gload16(&A[(m0 + row) * 768 + k0 + lc], &As[c * 512]);
            gload16(&Bt[(n0 + row) * 768 + k0 + lc], &Bs[c * 512]);
        }
        __syncthreads();
        for (int ks = 0; ks < 2; ++ks) {
            bf16x8 a[4], b[4];
            for (int i = 0; i < 4; ++i)
                a[i] = *(const bf16x8*)&As[(wm + i * 16 + ln) * 64 + ks * 32 + quad * 8];
            for (int j = 0; j < 4; ++j)
                b[j] = *(const bf16x8*)&Bs[(wn + j * 16 + ln) * 64 + ks * 32 + quad * 8];
            if (which == 2) {
                for (int i = 0; i < 4; ++i)
                    for (int j = 0; j < 4; ++j)
                        acc[i][j] = __builtin_amdgcn_mfma_f32_16x16x32_bf16(b[j], a[i], acc[i][j], 0, 0, 0);
            } else {
                for (int i = 0; i < 4; ++i)
                    for (int j = 0; j < 4; ++j)
                        acc[i][j] = __builtin_amdgcn_mfma_f32_16x16x32_bf16(a[i], b[j], acc[i][j], 0, 0, 0);
            }
        }
    }

    const float QSCALE = 0.125f * 1.44269504088896f;  // fold softmax scale * log2(e)
    if (which == 2) {
        // acc[i][j] = C^T block: row (quad*4+r) = weight idx wn+j*16+quad*4+r,
        // col (ln) = token wm+i*16+ln
        for (int i = 0; i < 4; ++i) {
            int gm = m0 + wm + i * 16 + ln;          // token
            int bb = gm >> 11, ss = gm & 2047;
            for (int j = 0; j < 4; ++j) {
                for (int r = 0; r < 4; ++r) {
                    int gn = n0 + wn + j * 16 + quad * 4 + r;   // weight idx
                    int h = gn >> 6, dd = gn & 63;
                    float v = acc[i][j][r] + bias[gn];
                    Vtb[(((size_t)bb * 12 + h) * 64 + dd) * 2048 + ss] = f2bf(v);
                }
            }
        }
    } else {
        for (int i = 0; i < 4; ++i) {
            for (int j = 0; j < 4; ++j) {
                int gn = n0 + wn + j * 16 + ln;   // 0..767
                float bia = bias[gn];
                int h = gn >> 6, dd = gn & 63;
                for (int r = 0; r < 4; ++r) {
                    int gm = m0 + wm + i * 16 + quad * 4 + r;
                    int bb = gm >> 11, ss = gm & 2047;
                    float v = acc[i][j][r] + bia;
                    if (which == 0) {
                        Qb[((bb * 12 + h) * 2048 + ss) * 64 + dd] = f2bf(v * QSCALE);
                    } else {
                        Kb[((bb * 12 + h) * 2048 + ss) * 64 + dd] = f2bf(v);
                    }
                }
            }
        }
    }
}

// ---------------------------------------------------------------- flash attention v5 (R7 exact)
__global__ __launch_bounds__(256) void attn_kernel(
    const ushort_t* __restrict__ Qb, const ushort_t* __restrict__ Kb,
    const ushort_t* __restrict__ Vtb, ushort_t* __restrict__ Ob) {
    __shared__ ushort_t Ks[2][64 * 72];
    __shared__ ushort_t Vs[2][64 * 72];
    int tid = threadIdx.x;
    int qt = blockIdx.x;   // 0..15
    int bh = blockIdx.y;   // 0..47
    int wave = tid >> 6;   // 0..3
    int ln = tid & 15;
    int quad = (tid >> 4) & 3;
    int q0 = qt * 128 + wave * 32;   // this wave's 32 q-columns

    const ushort_t* Qp = Qb + (size_t)bh * 2048 * 64;
    const ushort_t* Kp = Kb + (size_t)bh * 2048 * 64;
    const ushort_t* Vp = Vtb + (size_t)bh * 64 * 2048;

    // Q B-fragments (loop-invariant)
    bf16x8 bqf[2][2];
    for (int g = 0; g < 2; ++g)
        for (int ks = 0; ks < 2; ++ks)
            bqf[g][ks] = *(const bf16x8*)&Qp[(q0 + g * 16 + ln) * 64 + ks * 32 + quad * 8];

    // staging indices
    int srow = tid >> 3;            // 0..31 (K rows / V d-rows)
    int c8 = tid & 7;               // 16B chunk within 64 keys
    int scol = c8 * 8;
    int u = c8 & 3;
    int vcol = (c8 >> 2) * 32 + (u & 1) * 16 + (u >> 1) * 4;   // sigma-permuted base

    uint4 kreg[2], vreg[2];

    // prologue: panel 0
    for (int p = 0; p < 2; ++p) {
        kreg[p] = *(const uint4*)&Kp[(p * 32 + srow) * 64 + scol];
        vreg[p] = *(const uint4*)&Vp[(p * 32 + srow) * 2048 + scol];
    }
    for (int p = 0; p < 2; ++p) {
        *(uint4*)&Ks[0][(p * 32 + srow) * 72 + scol] = kreg[p];
        ushort_t* vb = &Vs[0][(p * 32 + srow) * 72 + vcol];
        *(uint2*)vb = make_uint2(vreg[p].x, vreg[p].y);
        *(uint2*)(vb + 8) = make_uint2(vreg[p].z, vreg[p].w);
    }
    __syncthreads();

    floatx4 o_acc[2][4];
    float lsum[2] = {0.f, 0.f};
    floatx4 z = {0.f, 0.f, 0.f, 0.f};
    for (int g = 0; g < 2; ++g)
        for (int m4 = 0; m4 < 4; ++m4) o_acc[g][m4] = z;

    for (int kt = 0; kt < 32; ++kt) {
        int cur = kt & 1;
        if (kt < 31) {
            for (int p = 0; p < 2; ++p) {
                kreg[p] = *(const uint4*)&Kp[((kt + 1) * 64 + p * 32 + srow) * 64 + scol];
                vreg[p] = *(const uint4*)&Vp[(p * 32 + srow) * 2048 + (kt + 1) * 64 + scol];
            }
        }

        const ushort_t* KsH = Ks[cur];
        const ushort_t* VsH = Vs[cur];

        // K A-frags
        bf16x8 ak[4][2];
        for (int m4 = 0; m4 < 4; ++m4)
            for (int ks = 0; ks < 2; ++ks)
                ak[m4][ks] = *(const bf16x8*)&KsH[(m4 * 16 + ln) * 72 + ks * 32 + quad * 8];

        // S^T = K Q^T
        floatx4 st[2][4];
        for (int g = 0; g < 2; ++g)
            for (int m4 = 0; m4 < 4; ++m4) {
                floatx4 s = z;
                s = __builtin_amdgcn_mfma_f32_16x16x32_bf16(ak[m4][0], bqf[g][0], s, 0, 0, 0);
                s = __builtin_amdgcn_mfma_f32_16x16x32_bf16(ak[m4][1], bqf[g][1], s, 0, 0, 0);
                st[g][m4] = s;
            }

        // P^T = 2^(S^T); per-lane column partial sums
        float pv[2][4][4];
        for (int g = 0; g < 2; ++g)
            for (int m4 = 0; m4 < 4; ++m4)
                for (int r = 0; r < 4; ++r) {
                    float e = __builtin_amdgcn_exp2f(st[g][m4][r]);
                    pv[g][m4][r] = e;
                    lsum[g] += e;
                }

        // V^T A-frags (pre-permuted, contiguous b128)
        bf16x8 av[4][2];
        for (int m4 = 0; m4 < 4; ++m4)
            for (int c = 0; c < 2; ++c)
                av[m4][c] = *(const bf16x8*)&VsH[(m4 * 16 + ln) * 72 + c * 32 + quad * 8];

        // Pack P^T B-frags (sigma order) and accumulate O^T
        for (int g = 0; g < 2; ++g) {
            bf16x8 bp[2];
            for (int c = 0; c < 2; ++c) {
                bf16x8 b;
                b[0] = (__bf16)pv[g][2 * c][0];
                b[1] = (__bf16)pv[g][2 * c][1];
                b[2] = (__bf16)pv[g][2 * c][2];
                b[3] = (__bf16)pv[g][2 * c][3];
                b[4] = (__bf16)pv[g][2 * c + 1][0];
                b[5] = (__bf16)pv[g][2 * c + 1][1];
                b[6] = (__bf16)pv[g][2 * c + 1][2];
                b[7] = (__bf16)pv[g][2 * c + 1][3];
                bp[c] = b;
            }
            for (int m4 = 0; m4 < 4; ++m4)
                for (int c = 0; c < 2; ++c)
                    o_acc[g][m4] = __builtin_amdgcn_mfma_f32_16x16x32_bf16(av[m4][c], bp[c], o_acc[g][m4], 0, 0, 0);
        }

        // write prefetched panel into the other buffer
        if (kt < 31) {
            int nxt = cur ^ 1;
            for (int p = 0; p < 2; ++p) {
                *(uint4*)&Ks[nxt][(p * 32 + srow) * 72 + scol] = kreg[p];
                ushort_t* vb = &Vs[nxt][(p * 32 + srow) * 72 + vcol];
                *(uint2*)vb = make_uint2(vreg[p].x, vreg[p].y);
                *(uint2*)(vb + 8) = make_uint2(vreg[p].z, vreg[p].w);
            }
        }
        __syncthreads();
    }

    // column sums: combine the 4 quads (lane&15 preserved)
    for (int g = 0; g < 2; ++g) {
        lsum[g] += __shfl_xor(lsum[g], 16);
        lsum[g] += __shfl_xor(lsum[g], 32);
    }

    int b = bh / 12, h = bh % 12;
    for (int g = 0; g < 2; ++g) {
        float inv = 1.f / lsum[g];
        int token = b * 2048 + q0 + g * 16 + ln;
        for (int m4 = 0; m4 < 4; ++m4)
            for (int r = 0; r < 4; ++r)
                Ob[token * 768 + h * 64 + m4 * 16 + quad * 4 + r] = f2bf(o_acc[g][m4][r] * inv);
    }
}

// ---------------------------------------------------------------- output projection (fp32 out, m97-style)
__global__ __launch_bounds__(256) void gemm_out(
    const ushort_t* __restrict__ A, const ushort_t* __restrict__ Bt,
    const float* __restrict__ bias, float* __restrict__ out) {
    __shared__ ushort_t As[128 * 64];
    __shared__ ushort_t Bs[128 * 64];
    int tid = threadIdx.x;
    int m0 = blockIdx.x * 128;
    int n0 = blockIdx.y * 128;

    int wave = tid >> 6;
    int lane = tid & 63;
    int ln = tid & 15;
    int quad = (tid >> 4) & 3;
    int wm = (wave & 1) * 64;
    int wn = (wave >> 1) * 64;
    int lr = lane >> 3;
    int lc = (lane & 7) * 8;

    floatx4 acc[4][4];
    floatx4 z = {0.f, 0.f, 0.f, 0.f};
    for (int i = 0; i < 4; ++i)
        for (int j = 0; j < 4; ++j) acc[i][j] = z;

    for (int kt = 0; kt < 12; ++kt) {
        int k0 = kt * 64;
        __syncthreads();
        for (int i = 0; i < 4; ++i) {
            int c = wave * 4 + i;
            int row = c * 8 + lr;
            gload16(&A[(m0 + row) * 768 + k0 + lc], &As[c * 512]);
            gload16(&Bt[(n0 + row) * 768 + k0 + lc], &Bs[c * 512]);
        }
        __syncthreads();
        for (int ks = 0; ks < 2; ++ks) {
            bf16x8 a[4], b[4];
            for (int i = 0; i < 4; ++i)
                a[i] = *(const bf16x8*)&As[(wm + i * 16 + ln) * 64 + ks * 32 + quad * 8];
            for (int j = 0; j < 4; ++j)
                b[j] = *(const bf16x8*)&Bs[(wn + j * 16 + ln) * 64 + ks * 32 + quad * 8];
            for (int i = 0; i < 4; ++i)
                for (int j = 0; j < 4; ++j)
                    acc[i][j] = __builtin_amdgcn_mfma_f32_16x16x32_bf16(a[i], b[j], acc[i][j], 0, 0, 0);
        }
    }

    for (int i = 0; i < 4; ++i) {
        for (int j = 0; j < 4; ++j) {
            int gn = n0 + wn + j * 16 + ln;
            float bia = bias[gn];
            for (int r = 0; r < 4; ++r) {
                int gm = m0 + wm + i * 16 + quad * 4 + r;
                out[gm * 768 + gn] = acc[i][j][r] + bia;
            }
        }
    }
}

extern "C" void kernel_launch(void* const* d_in, const int* in_sizes, int n_in,
                              void* d_out, int out_size, void* d_ws, size_t ws_size,
                              hipStream_t stream) {
    const float* x  = (const float*)d_in[0];
    const float* Wq = (const float*)d_in[1];
    const float* bq = (const float*)d_in[2];
    const float* Wk = (const float*)d_in[3];
    const float* bk = (const float*)d_in[4];
    const float* Wv = (const float*)d_in[5];
    const float* bv = (const float*)d_in[6];
    const float* Wo = (const float*)d_in[7];
    const float* bo = (const float*)d_in[8];

    const int NTOK = 4 * 2048;        // 8192
    const int NELT = NTOK * 768;      // 6291456
    const int WELT = 768 * 768;       // 589824

    ushort_t* xbf = (ushort_t*)d_ws;
    ushort_t* Tq  = xbf + NELT;
    ushort_t* Tk  = Tq + WELT;
    ushort_t* Tv  = Tk + WELT;
    ushort_t* To  = Tv + WELT;
    ushort_t* Qb  = To + WELT;
    ushort_t* Kb  = Qb + NELT;
    ushort_t* Vtb = Kb + NELT;
    ushort_t* Ob  = Vtb + NELT;

    prep_kernel<<<8448, 256, 0, stream>>>(x, xbf, Wq, Wk, Wv, Wo, Tq, Tk, Tv, To);
    gemm_qkv<<<dim3(64, 18), 256, 0, stream>>>(xbf, Tq, Tk, Tv, bq, bk, bv, Qb, Kb, Vtb);
    attn_kernel<<<dim3(16, 48), 256, 0, stream>>>(Qb, Kb, Vtb, Ob);
    gemm_out<<<dim3(64, 6), 256, 0, stream>>>(Ob, To, bo, (float*)d_out);
}

// Round 10
// 230.999 us; speedup vs baseline: 1.1472x; 1.1472x over previous
//
#include <hip/hip_runtime.h>

typedef unsigned short ushort_t;
typedef __bf16 bf16x8 __attribute__((ext_vector_type(8)));
typedef float floatx4 __attribute__((ext_vector_type(4)));

__device__ inline ushort_t f2bf(float f) {
    __bf16 h = (__bf16)f;
    return __builtin_bit_cast(ushort_t, h);
}

__device__ inline void gload16(const void* g, void* l) {
    __builtin_amdgcn_global_load_lds((const __attribute__((address_space(1))) void*)g,
                                     (__attribute__((address_space(3))) void*)l, 16, 0, 0);
}

// ---------------------------------------------------------------- prep: wt transpose (blocks 0..2303) + cast x (blocks 2304..8447)
__global__ __launch_bounds__(256) void prep_kernel(
    const float* __restrict__ x, ushort_t* __restrict__ xbf,
    const float* __restrict__ W0, const float* __restrict__ W1,
    const float* __restrict__ W2, const float* __restrict__ W3,
    ushort_t* __restrict__ T0, ushort_t* __restrict__ T1,
    ushort_t* __restrict__ T2, ushort_t* __restrict__ T3) {
    int bx = blockIdx.x;
    int tid = threadIdx.x;
    if (bx < 2304) {
        __shared__ float t[32][33];
        int w = bx / 576, rem = bx % 576;
        const float* W; ushort_t* T;
        switch (w) {
            case 0: W = W0; T = T0; break;
            case 1: W = W1; T = T1; break;
            case 2: W = W2; T = T2; break;
            default: W = W3; T = T3; break;
        }
        int n0 = (rem / 24) * 32, k0 = (rem % 24) * 32;
        int tx = tid & 31, ty = tid >> 5;   // 32 x 8
        for (int i = 0; i < 4; ++i)
            t[ty + i * 8][tx] = W[(k0 + ty + i * 8) * 768 + n0 + tx];
        __syncthreads();
        for (int i = 0; i < 4; ++i)
            T[(n0 + ty + i * 8) * 768 + k0 + tx] = f2bf(t[tx][ty + i * 8]);
    } else {
        int i = ((bx - 2304) * 256 + tid) * 4;
        float4 v = *(const float4*)(x + i);
        ushort4 u;
        u.x = f2bf(v.x); u.y = f2bf(v.y); u.z = f2bf(v.z); u.w = f2bf(v.w);
        *(ushort4*)(xbf + i) = u;
    }
}

// ---------------------------------------------------------------- fused QKV GEMM
// 128(M)x64(N) tiles -> 2304 blocks (9/CU) for latency hiding. m97 staging.
// Q pre-scaled by 0.125*log2(e).
__global__ __launch_bounds__(256) void gemm_qkv(
    const ushort_t* __restrict__ A,
    const ushort_t* __restrict__ Tq, const ushort_t* __restrict__ Tk, const ushort_t* __restrict__ Tv,
    const float* __restrict__ bq, const float* __restrict__ bk, const float* __restrict__ bv,
    ushort_t* __restrict__ Qb, ushort_t* __restrict__ Kb, ushort_t* __restrict__ Vtb) {
    __shared__ ushort_t As[128 * 64];   // 16 KB
    __shared__ ushort_t Bs[64 * 64];    // 8 KB
    int tid = threadIdx.x;
    int m0 = blockIdx.x * 128;
    int by = blockIdx.y;       // 0..35
    int which = by / 12;
    int n0 = (by % 12) * 64;
    const ushort_t* Bt = which == 0 ? Tq : (which == 1 ? Tk : Tv);
    const float* bias = which == 0 ? bq : (which == 1 ? bk : bv);

    int wave = tid >> 6;
    int lane = tid & 63;
    int ln = tid & 15;
    int quad = (tid >> 4) & 3;
    int wm = wave * 32;          // wave's 32 M-rows
    int lr = lane >> 3;          // 0..7
    int lc = (lane & 7) * 8;     // element col in 64

    floatx4 acc[2][4];
    floatx4 z = {0.f, 0.f, 0.f, 0.f};
    for (int i = 0; i < 2; ++i)
        for (int j = 0; j < 4; ++j) acc[i][j] = z;

    for (int kt = 0; kt < 12; ++kt) {
        int k0 = kt * 64;
        __syncthreads();
        for (int i = 0; i < 4; ++i) {            // A: 16 chunks of 8 rows
            int c = wave * 4 + i;
            gload16(&A[(m0 + c * 8 + lr) * 768 + k0 + lc], &As[c * 512]);
        }
        for (int i = 0; i < 2; ++i) {            // B: 8 chunks
            int c = wave * 2 + i;
            gload16(&Bt[(n0 + c * 8 + lr) * 768 + k0 + lc], &Bs[c * 512]);
        }
        __syncthreads();
        for (int ks = 0; ks < 2; ++ks) {
            bf16x8 a[2], b[4];
            for (int i = 0; i < 2; ++i)
                a[i] = *(const bf16x8*)&As[(wm + i * 16 + ln) * 64 + ks * 32 + quad * 8];
            for (int j = 0; j < 4; ++j)
                b[j] = *(const bf16x8*)&Bs[(j * 16 + ln) * 64 + ks * 32 + quad * 8];
            for (int i = 0; i < 2; ++i)
                for (int j = 0; j < 4; ++j)
                    acc[i][j] = __builtin_amdgcn_mfma_f32_16x16x32_bf16(a[i], b[j], acc[i][j], 0, 0, 0);
        }
    }

    const float QSCALE = 0.125f * 1.44269504088896f;  // fold softmax scale * log2(e)
    for (int i = 0; i < 2; ++i) {
        for (int j = 0; j < 4; ++j) {
            int gn = n0 + j * 16 + ln;        // 0..767
            float bia = bias[gn];
            int h = gn >> 6, dd = gn & 63;
            for (int r = 0; r < 4; ++r) {
                int gm = m0 + wm + i * 16 + quad * 4 + r;
                int bb = gm >> 11, ss = gm & 2047;
                float v = acc[i][j][r] + bia;
                if (which == 0) {
                    Qb[((bb * 12 + h) * 2048 + ss) * 64 + dd] = f2bf(v * QSCALE);
                } else if (which == 1) {
                    Kb[((bb * 12 + h) * 2048 + ss) * 64 + dd] = f2bf(v);
                } else {
                    Vtb[((bb * 12 + h) * 64 + dd) * 2048 + ss] = f2bf(v);
                }
            }
        }
    }
}

// ---------------------------------------------------------------- flash attention (R7 exact)
__global__ __launch_bounds__(256) void attn_kernel(
    const ushort_t* __restrict__ Qb, const ushort_t* __restrict__ Kb,
    const ushort_t* __restrict__ Vtb, ushort_t* __restrict__ Ob) {
    __shared__ ushort_t Ks[2][64 * 72];
    __shared__ ushort_t Vs[2][64 * 72];
    int tid = threadIdx.x;
    int qt = blockIdx.x;   // 0..15
    int bh = blockIdx.y;   // 0..47
    int wave = tid >> 6;   // 0..3
    int ln = tid & 15;
    int quad = (tid >> 4) & 3;
    int q0 = qt * 128 + wave * 32;   // this wave's 32 q-columns

    const ushort_t* Qp = Qb + (size_t)bh * 2048 * 64;
    const ushort_t* Kp = Kb + (size_t)bh * 2048 * 64;
    const ushort_t* Vp = Vtb + (size_t)bh * 64 * 2048;

    // Q B-fragments (loop-invariant)
    bf16x8 bqf[2][2];
    for (int g = 0; g < 2; ++g)
        for (int ks = 0; ks < 2; ++ks)
            bqf[g][ks] = *(const bf16x8*)&Qp[(q0 + g * 16 + ln) * 64 + ks * 32 + quad * 8];

    // staging indices
    int srow = tid >> 3;            // 0..31 (K rows / V d-rows)
    int c8 = tid & 7;               // 16B chunk within 64 keys
    int scol = c8 * 8;
    int u = c8 & 3;
    int vcol = (c8 >> 2) * 32 + (u & 1) * 16 + (u >> 1) * 4;   // sigma-permuted base

    uint4 kreg[2], vreg[2];

    // prologue: panel 0
    for (int p = 0; p < 2; ++p) {
        kreg[p] = *(const uint4*)&Kp[(p * 32 + srow) * 64 + scol];
        vreg[p] = *(const uint4*)&Vp[(p * 32 + srow) * 2048 + scol];
    }
    for (int p = 0; p < 2; ++p) {
        *(uint4*)&Ks[0][(p * 32 + srow) * 72 + scol] = kreg[p];
        ushort_t* vb = &Vs[0][(p * 32 + srow) * 72 + vcol];
        *(uint2*)vb = make_uint2(vreg[p].x, vreg[p].y);
        *(uint2*)(vb + 8) = make_uint2(vreg[p].z, vreg[p].w);
    }
    __syncthreads();

    floatx4 o_acc[2][4];
    float lsum[2] = {0.f, 0.f};
    floatx4 z = {0.f, 0.f, 0.f, 0.f};
    for (int g = 0; g < 2; ++g)
        for (int m4 = 0; m4 < 4; ++m4) o_acc[g][m4] = z;

    for (int kt = 0; kt < 32; ++kt) {
        int cur = kt & 1;
        if (kt < 31) {
            for (int p = 0; p < 2; ++p) {
                kreg[p] = *(const uint4*)&Kp[((kt + 1) * 64 + p * 32 + srow) * 64 + scol];
                vreg[p] = *(const uint4*)&Vp[(p * 32 + srow) * 2048 + (kt + 1) * 64 + scol];
            }
        }

        const ushort_t* KsH = Ks[cur];
        const ushort_t* VsH = Vs[cur];

        // K A-frags
        bf16x8 ak[4][2];
        for (int m4 = 0; m4 < 4; ++m4)
            for (int ks = 0; ks < 2; ++ks)
                ak[m4][ks] = *(const bf16x8*)&KsH[(m4 * 16 + ln) * 72 + ks * 32 + quad * 8];

        // S^T = K Q^T
        floatx4 st[2][4];
        for (int g = 0; g < 2; ++g)
            for (int m4 = 0; m4 < 4; ++m4) {
                floatx4 s = z;
                s = __builtin_amdgcn_mfma_f32_16x16x32_bf16(ak[m4][0], bqf[g][0], s, 0, 0, 0);
                s = __builtin_amdgcn_mfma_f32_16x16x32_bf16(ak[m4][1], bqf[g][1], s, 0, 0, 0);
                st[g][m4] = s;
            }

        // P^T = 2^(S^T); per-lane column partial sums
        float pv[2][4][4];
        for (int g = 0; g < 2; ++g)
            for (int m4 = 0; m4 < 4; ++m4)
                for (int r = 0; r < 4; ++r) {
                    float e = __builtin_amdgcn_exp2f(st[g][m4][r]);
                    pv[g][m4][r] = e;
                    lsum[g] += e;
                }

        // V^T A-frags (pre-permuted, contiguous b128)
        bf16x8 av[4][2];
        for (int m4 = 0; m4 < 4; ++m4)
            for (int c = 0; c < 2; ++c)
                av[m4][c] = *(const bf16x8*)&VsH[(m4 * 16 + ln) * 72 + c * 32 + quad * 8];

        // Pack P^T B-frags (sigma order) and accumulate O^T
        for (int g = 0; g < 2; ++g) {
            bf16x8 bp[2];
            for (int c = 0; c < 2; ++c) {
                bf16x8 b;
                b[0] = (__bf16)pv[g][2 * c][0];
                b[1] = (__bf16)pv[g][2 * c][1];
                b[2] = (__bf16)pv[g][2 * c][2];
                b[3] = (__bf16)pv[g][2 * c][3];
                b[4] = (__bf16)pv[g][2 * c + 1][0];
                b[5] = (__bf16)pv[g][2 * c + 1][1];
                b[6] = (__bf16)pv[g][2 * c + 1][2];
                b[7] = (__bf16)pv[g][2 * c + 1][3];
                bp[c] = b;
            }
            for (int m4 = 0; m4 < 4; ++m4)
                for (int c = 0; c < 2; ++c)
                    o_acc[g][m4] = __builtin_amdgcn_mfma_f32_16x16x32_bf16(av[m4][c], bp[c], o_acc[g][m4], 0, 0, 0);
        }

        // write prefetched panel into the other buffer
        if (kt < 31) {
            int nxt = cur ^ 1;
            for (int p = 0; p < 2; ++p) {
                *(uint4*)&Ks[nxt][(p * 32 + srow) * 72 + scol] = kreg[p];
                ushort_t* vb = &Vs[nxt][(p * 32 + srow) * 72 + vcol];
                *(uint2*)vb = make_uint2(vreg[p].x, vreg[p].y);
                *(uint2*)(vb + 8) = make_uint2(vreg[p].z, vreg[p].w);
            }
        }
        __syncthreads();
    }

    // column sums: combine the 4 quads (lane&15 preserved)
    for (int g = 0; g < 2; ++g) {
        lsum[g] += __shfl_xor(lsum[g], 16);
        lsum[g] += __shfl_xor(lsum[g], 32);
    }

    int b = bh / 12, h = bh % 12;
    for (int g = 0; g < 2; ++g) {
        float inv = 1.f / lsum[g];
        int token = b * 2048 + q0 + g * 16 + ln;
        for (int m4 = 0; m4 < 4; ++m4)
            for (int r = 0; r < 4; ++r)
                Ob[token * 768 + h * 64 + m4 * 16 + quad * 4 + r] = f2bf(o_acc[g][m4][r] * inv);
    }
}

// ---------------------------------------------------------------- output projection (fp32 out)
// 64x64 tiles -> 1536 blocks (6/CU). Each wave owns a 16-col slice.
__global__ __launch_bounds__(256) void gemm_out(
    const ushort_t* __restrict__ A, const ushort_t* __restrict__ Bt,
    const float* __restrict__ bias, float* __restrict__ out) {
    __shared__ ushort_t As[64 * 64];   // 8 KB
    __shared__ ushort_t Bs[64 * 64];   // 8 KB
    int tid = threadIdx.x;
    int m0 = blockIdx.x * 64;
    int n0 = blockIdx.y * 64;

    int wave = tid >> 6;
    int lane = tid & 63;
    int ln = tid & 15;
    int quad = (tid >> 4) & 3;
    int lr = lane >> 3;
    int lc = (lane & 7) * 8;

    floatx4 acc[4];
    floatx4 z = {0.f, 0.f, 0.f, 0.f};
    for (int i = 0; i < 4; ++i) acc[i] = z;

    for (int kt = 0; kt < 12; ++kt) {
        int k0 = kt * 64;
        __syncthreads();
        for (int i = 0; i < 2; ++i) {
            int c = wave * 2 + i;   // 8 chunks each
            gload16(&A[(m0 + c * 8 + lr) * 768 + k0 + lc], &As[c * 512]);
            gload16(&Bt[(n0 + c * 8 + lr) * 768 + k0 + lc], &Bs[c * 512]);
        }
        __syncthreads();
        for (int ks = 0; ks < 2; ++ks) {
            bf16x8 b = *(const bf16x8*)&Bs[(wave * 16 + ln) * 64 + ks * 32 + quad * 8];
            for (int i = 0; i < 4; ++i) {
                bf16x8 a = *(const bf16x8*)&As[(i * 16 + ln) * 64 + ks * 32 + quad * 8];
                acc[i] = __builtin_amdgcn_mfma_f32_16x16x32_bf16(a, b, acc[i], 0, 0, 0);
            }
        }
    }

    int gn = n0 + wave * 16 + ln;
    float bia = bias[gn];
    for (int i = 0; i < 4; ++i) {
        for (int r = 0; r < 4; ++r) {
            int gm = m0 + i * 16 + quad * 4 + r;
            out[gm * 768 + gn] = acc[i][r] + bia;
        }
    }
}

extern "C" void kernel_launch(void* const* d_in, const int* in_sizes, int n_in,
                              void* d_out, int out_size, void* d_ws, size_t ws_size,
                              hipStream_t stream) {
    const float* x  = (const float*)d_in[0];
    const float* Wq = (const float*)d_in[1];
    const float* bq = (const float*)d_in[2];
    const float* Wk = (const float*)d_in[3];
    const float* bk = (const float*)d_in[4];
    const float* Wv = (const float*)d_in[5];
    const float* bv = (const float*)d_in[6];
    const float* Wo = (const float*)d_in[7];
    const float* bo = (const float*)d_in[8];

    const int NTOK = 4 * 2048;        // 8192
    const int NELT = NTOK * 768;      // 6291456
    const int WELT = 768 * 768;       // 589824

    ushort_t* xbf = (ushort_t*)d_ws;
    ushort_t* Tq  = xbf + NELT;
    ushort_t* Tk  = Tq + WELT;
    ushort_t* Tv  = Tk + WELT;
    ushort_t* To  = Tv + WELT;
    ushort_t* Qb  = To + WELT;
    ushort_t* Kb  = Qb + NELT;
    ushort_t* Vtb = Kb + NELT;
    ushort_t* Ob  = Vtb + NELT;

    prep_kernel<<<8448, 256, 0, stream>>>(x, xbf, Wq, Wk, Wv, Wo, Tq, Tk, Tv, To);
    gemm_qkv<<<dim3(64, 36), 256, 0, stream>>>(xbf, Tq, Tk, Tv, bq, bk, bv, Qb, Kb, Vtb);
    attn_kernel<<<dim3(16, 48), 256, 0, stream>>>(Qb, Kb, Vtb, Ob);
    gemm_out<<<dim3(128, 12), 256, 0, stream>>>(Ob, To, bo, (float*)d_out);
}